// Round 3
// baseline (75.644 us; speedup 1.0000x reference)
//
#include <hip/hip_runtime.h>
#include <math.h>

// Problem constants (fixed by reference setup_inputs)
#define N_TOT 8192
#define M_TOT 16384
#define EPS_N 1024      // M / N_EMB
#define N_EMB 16

#define LOG2E 1.4426950408889634f
#define LN2   0.6931471805599453f
#define EXP2(x) __builtin_amdgcn_exp2f(x)   // v_exp_f32
#define LOG2F_(x) __builtin_amdgcn_logf(x)  // v_log_f32 (log2)

// K1 tiling: product-grid factorization e_j = m_k + T*u_l  (j = k*1024 + l)
//   t_ij = A_ik + B_il,  P=2^A (8192x16), Q=2^B (8192x1024), S_kl = sum_i P_ik Q_il
// Round-3 geometry: 4 l's per lane (LCH=256) halves LDS-broadcast traffic and
// phase-A exp duplication vs LCH=128; IC=64 keeps 512 blocks (2/CU).
#define BLOCK 256
#define IC    64             // i's per block
#define NICH  (N_TOT / IC)   // 128 i-chunks
#define LCH   256            // l's per block
#define NLCH  (EPS_N / LCH)  // 4 l-chunks

// Kernel 1: gemm partials. Plain stores only — kernel boundary provides
// coherence (round-1 lesson: intra-kernel __threadfence = buffer_wbl2 x512).
// Also zeroes the k2 election counter (saves the memset dispatch; the store
// rides the same end-of-kernel L2 writeback that makes `part` visible).
__global__ __launch_bounds__(BLOCK) void gemm_partial_kernel(
    const float* __restrict__ z, const float* __restrict__ emb,
    const float* __restrict__ log_sigma, const float* __restrict__ eps,
    const float* __restrict__ temperature, float* __restrict__ part,
    unsigned int* __restrict__ cnt)
{
    // per i: slots 0..3 = P[k=0..15] as float4s, slot 4 = (T*b0, T*b1, -, -)
    __shared__ float4 rows[IC * 5];              // 5 KB
    __shared__ float red[4][N_EMB * 128];        // 32 KB, reused for two l-halves

    const int t  = threadIdx.x;
    const int l0 = blockIdx.x * LCH;
    const int ib = blockIdx.y;

    if (t == 0 && blockIdx.x == 0 && blockIdx.y == 0)
        cnt[0] = 0u;                             // visible to k2 via kernel-boundary release

    const float ls = log_sigma[0];
    const float T  = temperature[0];
    const float alpha = -0.5f * EXP2(LOG2E * (-2.0f * ls));  // -1/(2 sigma^2)
    const float La  = LOG2E * alpha;
    const float omT = 1.0f - T;

    // Phase A: stage P-rows. 256 threads cover 64 i's x 4 k-quads (4 exps each).
    {
        const int il = t & (IC - 1);
        const int kq = t >> 6;                   // 0..3, wave-uniform
        const int i  = ib * IC + il;
        const float z0 = z[2 * i], z1 = z[2 * i + 1];
        const float c  = La * (z0 * z0 + z1 * z1);
        const float b0 = -2.0f * La * z0, b1 = -2.0f * La * z1;
        float4 pa;
#pragma unroll
        for (int kk = 0; kk < 4; ++kk) {
            int k = kq * 4 + kk;
            float m0 = omT * emb[2 * k], m1 = omT * emb[2 * k + 1];
            ((float*)&pa)[kk] = EXP2(c + b0 * m0 + b1 * m1);   // P_ik
        }
        rows[il * 5 + kq] = pa;
        if (kq == 0)
            rows[il * 5 + 4] = make_float4(T * b0, T * b1, 0.0f, 0.0f);
    }

    // Each lane owns 4 l's: l0+lane, +64, +128, +192 (coalesced float2 loads)
    const int lane = t & 63;
    const int w    = t >> 6;
    const float2* eps2 = (const float2*)eps;
    const float2 ua = eps2[l0 + lane];
    const float2 ub = eps2[l0 + 64 + lane];
    const float2 uc = eps2[l0 + 128 + lane];
    const float2 ud = eps2[l0 + 192 + lane];

    __syncthreads();

    float sa[N_EMB] = {0.0f};
    float sb[N_EMB] = {0.0f};
    float sc_[N_EMB] = {0.0f};
    float sd[N_EMB] = {0.0f};
    // Each wave reduces its private 16-i subrange; rows reads are wave-uniform
    // (broadcast).  68 FMAs per 5 ds_read_b128 — 2x the VALU:LDS ratio of LCH=128.
#pragma unroll 2
    for (int n = 0; n < IC / 4; ++n) {
        const int ir = w * (IC / 4) + n;
        float4 p0 = rows[ir * 5 + 0];
        float4 p1 = rows[ir * 5 + 1];
        float4 p2 = rows[ir * 5 + 2];
        float4 p3 = rows[ir * 5 + 3];
        float4 tb = rows[ir * 5 + 4];
        float qa = EXP2(fmaf(tb.y, ua.y, tb.x * ua.x));   // Q_i,l
        float qb = EXP2(fmaf(tb.y, ub.y, tb.x * ub.x));
        float qc = EXP2(fmaf(tb.y, uc.y, tb.x * uc.x));
        float qd = EXP2(fmaf(tb.y, ud.y, tb.x * ud.x));
        float pk[16];
        *(float4*)&pk[0]  = p0; *(float4*)&pk[4]  = p1;
        *(float4*)&pk[8]  = p2; *(float4*)&pk[12] = p3;
#pragma unroll
        for (int k = 0; k < N_EMB; ++k) {
            sa[k]  = fmaf(pk[k], qa, sa[k]);
            sb[k]  = fmaf(pk[k], qb, sb[k]);
            sc_[k] = fmaf(pk[k], qc, sc_[k]);
            sd[k]  = fmaf(pk[k], qd, sd[k]);
        }
    }

    // Phase C: cross-wave reduce via LDS, two 128-l halves (red reused).
    // half 0: l-offsets [0,128) = sa (lane) + sb (lane+64)
#pragma unroll
    for (int k = 0; k < N_EMB; ++k) {
        red[w][k * 128 + lane]      = sa[k];
        red[w][k * 128 + 64 + lane] = sb[k];
    }
    __syncthreads();
#pragma unroll
    for (int r = 0; r < (N_EMB * 128) / BLOCK; ++r) {
        const int e  = t + r * BLOCK;
        const float S = red[0][e] + red[1][e] + red[2][e] + red[3][e];
        const int k  = e >> 7;
        const int ll = e & 127;
        part[ib * M_TOT + k * EPS_N + l0 + ll] = S;
    }
    __syncthreads();                             // red consumed; safe to overwrite
    // half 1: l-offsets [128,256) = sc_ (lane) + sd (lane+64)
#pragma unroll
    for (int k = 0; k < N_EMB; ++k) {
        red[w][k * 128 + lane]      = sc_[k];
        red[w][k * 128 + 64 + lane] = sd[k];
    }
    __syncthreads();
#pragma unroll
    for (int r = 0; r < (N_EMB * 128) / BLOCK; ++r) {
        const int e  = t + r * BLOCK;
        const float S = red[0][e] + red[1][e] + red[2][e] + red[3][e];
        const int k  = e >> 7;
        const int ll = e & 127;
        part[ib * M_TOT + k * EPS_N + l0 + 128 + ll] = S;
    }
}

// Kernel 2: per-j combine + in-kernel final election (proven in round 2).
// Only cross-block data INSIDE this kernel: 64 bsum floats + 1 counter, moved
// with agent-scope write-through atomics (sc0/sc1) — no L2 writeback fence.
__global__ __launch_bounds__(BLOCK) void reduce_final_kernel(
    const float* __restrict__ emb, const float* __restrict__ log_sigma,
    const float* __restrict__ eps, const float* __restrict__ temperature,
    const float* __restrict__ part, float* __restrict__ bsum,
    unsigned int* __restrict__ cnt, float* __restrict__ out)
{
    const int j = blockIdx.x * BLOCK + threadIdx.x;
    const float ls = log_sigma[0];
    const float T  = temperature[0];
    const float alpha = -0.5f * EXP2(LOG2E * (-2.0f * ls));

    float S = 0.0f;
#pragma unroll 16
    for (int ib = 0; ib < NICH; ++ib)
        S += part[ib * M_TOT + j];        // coalesced across threads; deep unroll for MLP

    const int k = j >> 10, l = j & (EPS_N - 1);
    const float omT = 1.0f - T;
    const float e0 = omT * emb[2 * k]     + T * eps[2 * l];
    const float e1 = omT * emb[2 * k + 1] + T * eps[2 * l + 1];
    const float g  = LOG2E * alpha * (e0 * e0 + e1 * e1);  // factored-out 2^g

    float v = g + LOG2F_(S);              // lse_j / ln2

#pragma unroll
    for (int off = 32; off; off >>= 1) v += __shfl_down(v, off, 64);
    __shared__ float wsum[BLOCK / 64];
    __shared__ unsigned int sdone;
    const int lane = threadIdx.x & 63, w = threadIdx.x >> 6;
    if (lane == 0) wsum[w] = v;
    __syncthreads();

    if (threadIdx.x == 0) {
        const float b = wsum[0] + wsum[1] + wsum[2] + wsum[3];
        // Write-through store to the coherent point (agent scope => sc0 sc1).
        __hip_atomic_store(&bsum[blockIdx.x], b, __ATOMIC_RELAXED,
                           __HIP_MEMORY_SCOPE_AGENT);
        // bsum store must land before the counter bump becomes visible.
        asm volatile("s_waitcnt vmcnt(0)" ::: "memory");
        const unsigned int old = __hip_atomic_fetch_add(
            &cnt[0], 1u, __ATOMIC_RELAXED, __HIP_MEMORY_SCOPE_AGENT);
        sdone = (old == (unsigned int)(M_TOT / BLOCK - 1)) ? 1u : 0u;
    }
    __syncthreads();
    if (sdone == 0u) return;              // not the last block

    // Last block: wave 0 sums the 64 block sums (fixed lane order: deterministic)
    if (threadIdx.x < 64) {
        float v2 = __hip_atomic_load(&bsum[threadIdx.x], __ATOMIC_RELAXED,
                                     __HIP_MEMORY_SCOPE_AGENT);
#pragma unroll
        for (int off = 32; off; off >>= 1) v2 += __shfl_down(v2, off, 64);
        if (threadIdx.x == 0) {
            const float sum_lse = v2 * LN2;   // sum_j lse_j
            // loss = -mean(lse) + 0.5*z_dim*(2*ls - 1) + log(n);  z_dim=2, n=8192
            out[0] = -sum_lse / (float)M_TOT + (2.0f * ls - 1.0f)
                     + 9.010913347279288f;
        }
    }
}

extern "C" void kernel_launch(void* const* d_in, const int* in_sizes, int n_in,
                              void* d_out, int out_size, void* d_ws, size_t ws_size,
                              hipStream_t stream)
{
    const float* z    = (const float*)d_in[0];
    const float* emb  = (const float*)d_in[1];
    const float* lsig = (const float*)d_in[2];
    const float* eps  = (const float*)d_in[3];
    const float* temp = (const float*)d_in[4];

    // ws layout: [0,64) counter (zeroed by k1), [64,320) bsum (64 floats,
    // fully overwritten before read), [512, 512+8MB) part.
    unsigned int* cnt = (unsigned int*)d_ws;
    float* bsum = (float*)d_ws + 16;               // offset 64 B
    float* part = (float*)d_ws + 128;              // offset 512 B

    dim3 grid1(NLCH, NICH);                        // 4 x 128 = 512 blocks
    gemm_partial_kernel<<<grid1, BLOCK, 0, stream>>>(z, emb, lsig, eps, temp,
                                                     part, cnt);
    reduce_final_kernel<<<M_TOT / BLOCK, BLOCK, 0, stream>>>(
        emb, lsig, eps, temp, part, bsum, cnt, (float*)d_out);
}

// Round 4
// 71.821 us; speedup vs baseline: 1.0532x; 1.0532x over previous
//
#include <hip/hip_runtime.h>
#include <math.h>

// Problem constants (fixed by reference setup_inputs)
#define N_TOT 8192
#define M_TOT 16384
#define EPS_N 1024      // M / N_EMB
#define N_EMB 16

#define LOG2E 1.4426950408889634f
#define LN2   0.6931471805599453f
#define EXP2(x) __builtin_amdgcn_exp2f(x)   // v_exp_f32
#define LOG2F_(x) __builtin_amdgcn_logf(x)  // v_log_f32 (log2)

// K1 tiling: product-grid factorization e_j = m_k + T*u_l  (j = k*1024 + l)
//   t_ij = A_ik + B_il,  P=2^A (8192x16), Q=2^B (8192x1024), S_kl = sum_i P_ik Q_il
// Round-4 geometry: LCH=256 (4 l's/lane) halves main-loop LDS reads per FMA
// vs LCH=128, while IC=128 keeps part at 4 MB (round-3 lesson: don't pay for
// LDS savings with HBM traffic). Grid 4x64 = 256 blocks = 1/CU.
#define BLOCK 256
#define IC    128            // i's per block
#define NICH  (N_TOT / IC)   // 64 i-chunks
#define LCH   256            // l's per block
#define NLCH  (EPS_N / LCH)  // 4 l-chunks

// Kernel 1: gemm partials. Plain stores only — kernel boundary provides
// coherence (round-1 lesson: intra-kernel __threadfence = buffer_wbl2 x512).
// Also zeroes the k2 election counter (saves the memset dispatch).
__global__ __launch_bounds__(BLOCK) void gemm_partial_kernel(
    const float* __restrict__ z, const float* __restrict__ emb,
    const float* __restrict__ log_sigma, const float* __restrict__ eps,
    const float* __restrict__ temperature, float* __restrict__ part,
    unsigned int* __restrict__ cnt)
{
    __shared__ float4 rowsP[IC][4];          // 8 KB: P[i][k] as 4 float4s
    __shared__ float2 tbv[IC];               // 1 KB: (T*b0, T*b1) per i -> ds_read_b64
    __shared__ float  red[4][N_EMB * 128];   // 32 KB, reused for two l-halves

    const int t  = threadIdx.x;
    const int l0 = blockIdx.x * LCH;
    const int ib = blockIdx.y;

    if (t == 0 && blockIdx.x == 0 && blockIdx.y == 0)
        cnt[0] = 0u;                         // visible to k2 via kernel-boundary release

    const float ls = log_sigma[0];
    const float T  = temperature[0];
    const float alpha = -0.5f * EXP2(LOG2E * (-2.0f * ls));  // -1/(2 sigma^2)
    const float La  = LOG2E * alpha;
    const float omT = 1.0f - T;

    // Phase A: stage P-rows. 256 threads cover 128 i's x 2 k-halves (8 exps each).
    {
        const int il = t & (IC - 1);
        const int kh = t >> 7;               // wave-uniform (waves 0,1 -> 0; 2,3 -> 1)
        const int i  = ib * IC + il;
        const float z0 = z[2 * i], z1 = z[2 * i + 1];
        const float c  = La * (z0 * z0 + z1 * z1);
        const float b0 = -2.0f * La * z0, b1 = -2.0f * La * z1;
        float4 pa, pb;
#pragma unroll
        for (int kk = 0; kk < 4; ++kk) {
            int k = kh * 8 + kk;
            float m0 = omT * emb[2 * k], m1 = omT * emb[2 * k + 1];
            ((float*)&pa)[kk] = EXP2(c + b0 * m0 + b1 * m1);   // P_ik
        }
#pragma unroll
        for (int kk = 0; kk < 4; ++kk) {
            int k = kh * 8 + 4 + kk;
            float m0 = omT * emb[2 * k], m1 = omT * emb[2 * k + 1];
            ((float*)&pb)[kk] = EXP2(c + b0 * m0 + b1 * m1);
        }
        rowsP[il][kh * 2]     = pa;
        rowsP[il][kh * 2 + 1] = pb;
        if (kh == 0)
            tbv[il] = make_float2(T * b0, T * b1);
    }

    // Each lane owns 4 l's: l0+lane, +64, +128, +192 (coalesced float2 loads)
    const int lane = t & 63;
    const int w    = t >> 6;
    const float2* eps2 = (const float2*)eps;
    const float2 ua = eps2[l0 + lane];
    const float2 ub = eps2[l0 + 64 + lane];
    const float2 uc = eps2[l0 + 128 + lane];
    const float2 ud = eps2[l0 + 192 + lane];

    __syncthreads();

    float sa[N_EMB] = {0.0f};
    float sb[N_EMB] = {0.0f};
    float sc_[N_EMB] = {0.0f};
    float sd[N_EMB] = {0.0f};
    // Each wave reduces its private 32-i subrange; rowsP/tbv reads are
    // wave-uniform (broadcast). 64 FMAs per (4x ds_read_b128 + 1x ds_read_b64).
#pragma unroll 2
    for (int n = 0; n < IC / 4; ++n) {
        const int ir = w * (IC / 4) + n;
        float4 p0 = rowsP[ir][0];
        float4 p1 = rowsP[ir][1];
        float4 p2 = rowsP[ir][2];
        float4 p3 = rowsP[ir][3];
        float2 tb = tbv[ir];
        float qa = EXP2(fmaf(tb.y, ua.y, tb.x * ua.x));   // Q_i,l
        float qb = EXP2(fmaf(tb.y, ub.y, tb.x * ub.x));
        float qc = EXP2(fmaf(tb.y, uc.y, tb.x * uc.x));
        float qd = EXP2(fmaf(tb.y, ud.y, tb.x * ud.x));
        float pk[16];
        *(float4*)&pk[0]  = p0; *(float4*)&pk[4]  = p1;
        *(float4*)&pk[8]  = p2; *(float4*)&pk[12] = p3;
#pragma unroll
        for (int k = 0; k < N_EMB; ++k) {
            sa[k]  = fmaf(pk[k], qa, sa[k]);
            sb[k]  = fmaf(pk[k], qb, sb[k]);
            sc_[k] = fmaf(pk[k], qc, sc_[k]);
            sd[k]  = fmaf(pk[k], qd, sd[k]);
        }
    }

    // Phase C: cross-wave reduce via LDS, two 128-l halves (red reused).
    // Reduce reads are float4-vectorized (linear layout: conflict-free) and
    // part stores are dwordx4.
    // half 0: l-offsets [0,128) = sa (lane) + sb (lane+64)
#pragma unroll
    for (int k = 0; k < N_EMB; ++k) {
        red[w][k * 128 + lane]      = sa[k];
        red[w][k * 128 + 64 + lane] = sb[k];
    }
    __syncthreads();
#pragma unroll
    for (int r = 0; r < 2; ++r) {
        const int eq = t + r * BLOCK;         // quad index, 512 quads
        const int e  = eq * 4;
        const float4 a0 = *(const float4*)&red[0][e];
        const float4 a1 = *(const float4*)&red[1][e];
        const float4 a2 = *(const float4*)&red[2][e];
        const float4 a3 = *(const float4*)&red[3][e];
        float4 S;
        S.x = a0.x + a1.x + a2.x + a3.x;
        S.y = a0.y + a1.y + a2.y + a3.y;
        S.z = a0.z + a1.z + a2.z + a3.z;
        S.w = a0.w + a1.w + a2.w + a3.w;
        const int k  = e >> 7;
        const int ll = e & 127;               // multiple of 4; quad stays in-row
        *(float4*)&part[ib * M_TOT + k * EPS_N + l0 + ll] = S;
    }
    __syncthreads();                          // red consumed; safe to overwrite
    // half 1: l-offsets [128,256) = sc_ (lane) + sd (lane+64)
#pragma unroll
    for (int k = 0; k < N_EMB; ++k) {
        red[w][k * 128 + lane]      = sc_[k];
        red[w][k * 128 + 64 + lane] = sd[k];
    }
    __syncthreads();
#pragma unroll
    for (int r = 0; r < 2; ++r) {
        const int eq = t + r * BLOCK;
        const int e  = eq * 4;
        const float4 a0 = *(const float4*)&red[0][e];
        const float4 a1 = *(const float4*)&red[1][e];
        const float4 a2 = *(const float4*)&red[2][e];
        const float4 a3 = *(const float4*)&red[3][e];
        float4 S;
        S.x = a0.x + a1.x + a2.x + a3.x;
        S.y = a0.y + a1.y + a2.y + a3.y;
        S.z = a0.z + a1.z + a2.z + a3.z;
        S.w = a0.w + a1.w + a2.w + a3.w;
        const int k  = e >> 7;
        const int ll = e & 127;
        *(float4*)&part[ib * M_TOT + k * EPS_N + l0 + 128 + ll] = S;
    }
}

// Kernel 2: per-j combine + in-kernel final election (proven in round 2).
// Only cross-block data INSIDE this kernel: 64 bsum floats + 1 counter, moved
// with agent-scope write-through atomics (sc0/sc1) — no L2 writeback fence.
__global__ __launch_bounds__(BLOCK) void reduce_final_kernel(
    const float* __restrict__ emb, const float* __restrict__ log_sigma,
    const float* __restrict__ eps, const float* __restrict__ temperature,
    const float* __restrict__ part, float* __restrict__ bsum,
    unsigned int* __restrict__ cnt, float* __restrict__ out)
{
    const int j = blockIdx.x * BLOCK + threadIdx.x;
    const float ls = log_sigma[0];
    const float T  = temperature[0];
    const float alpha = -0.5f * EXP2(LOG2E * (-2.0f * ls));

    float S = 0.0f;
#pragma unroll 16
    for (int ib = 0; ib < NICH; ++ib)
        S += part[ib * M_TOT + j];        // coalesced across threads; deep unroll for MLP

    const int k = j >> 10, l = j & (EPS_N - 1);
    const float omT = 1.0f - T;
    const float e0 = omT * emb[2 * k]     + T * eps[2 * l];
    const float e1 = omT * emb[2 * k + 1] + T * eps[2 * l + 1];
    const float g  = LOG2E * alpha * (e0 * e0 + e1 * e1);  // factored-out 2^g

    float v = g + LOG2F_(S);              // lse_j / ln2

#pragma unroll
    for (int off = 32; off; off >>= 1) v += __shfl_down(v, off, 64);
    __shared__ float wsum[BLOCK / 64];
    __shared__ unsigned int sdone;
    const int lane = threadIdx.x & 63, w = threadIdx.x >> 6;
    if (lane == 0) wsum[w] = v;
    __syncthreads();

    if (threadIdx.x == 0) {
        const float b = wsum[0] + wsum[1] + wsum[2] + wsum[3];
        // Write-through store to the coherent point (agent scope => sc0 sc1).
        __hip_atomic_store(&bsum[blockIdx.x], b, __ATOMIC_RELAXED,
                           __HIP_MEMORY_SCOPE_AGENT);
        // bsum store must land before the counter bump becomes visible.
        asm volatile("s_waitcnt vmcnt(0)" ::: "memory");
        const unsigned int old = __hip_atomic_fetch_add(
            &cnt[0], 1u, __ATOMIC_RELAXED, __HIP_MEMORY_SCOPE_AGENT);
        sdone = (old == (unsigned int)(M_TOT / BLOCK - 1)) ? 1u : 0u;
    }
    __syncthreads();
    if (sdone == 0u) return;              // not the last block

    // Last block: wave 0 sums the 64 block sums (fixed lane order: deterministic)
    if (threadIdx.x < 64) {
        float v2 = __hip_atomic_load(&bsum[threadIdx.x], __ATOMIC_RELAXED,
                                     __HIP_MEMORY_SCOPE_AGENT);
#pragma unroll
        for (int off = 32; off; off >>= 1) v2 += __shfl_down(v2, off, 64);
        if (threadIdx.x == 0) {
            const float sum_lse = v2 * LN2;   // sum_j lse_j
            // loss = -mean(lse) + 0.5*z_dim*(2*ls - 1) + log(n);  z_dim=2, n=8192
            out[0] = -sum_lse / (float)M_TOT + (2.0f * ls - 1.0f)
                     + 9.010913347279288f;
        }
    }
}

extern "C" void kernel_launch(void* const* d_in, const int* in_sizes, int n_in,
                              void* d_out, int out_size, void* d_ws, size_t ws_size,
                              hipStream_t stream)
{
    const float* z    = (const float*)d_in[0];
    const float* emb  = (const float*)d_in[1];
    const float* lsig = (const float*)d_in[2];
    const float* eps  = (const float*)d_in[3];
    const float* temp = (const float*)d_in[4];

    // ws layout: [0,64) counter (zeroed by k1), [64,320) bsum (64 floats,
    // fully overwritten before read), [512, 512+4MB) part.
    unsigned int* cnt = (unsigned int*)d_ws;
    float* bsum = (float*)d_ws + 16;               // offset 64 B
    float* part = (float*)d_ws + 128;              // offset 512 B

    dim3 grid1(NLCH, NICH);                        // 4 x 64 = 256 blocks (1/CU)
    gemm_partial_kernel<<<grid1, BLOCK, 0, stream>>>(z, emb, lsig, eps, temp,
                                                     part, cnt);
    reduce_final_kernel<<<M_TOT / BLOCK, BLOCK, 0, stream>>>(
        emb, lsig, eps, temp, part, bsum, cnt, (float*)d_out);
}